// Round 5
// baseline (93.313 us; speedup 1.0000x reference)
//
#include <hip/hip_runtime.h>
#include <hip/hip_fp16.h>
#include <cstdint>
#include <cstddef>

#define HH 240
#define WW 320
#define HWPIX 76800
#define NVIEW 4
#define NCH 32
#define NGRP 8
#define NDEP 8
#define NNEI 9
#define SPLANE (HWPIX * NCH)   // halfs per feature plane

// ws layout (in floats)
#define OFF_PROJ 0    // 4 views * 12 (rot 9 row-major, trans 3)
// packed net (157 floats each): [0..64) w0 as 128 f16 (16x8, BN*0.25 folded)
//                               [64..128) w1 as 128 f16 (8x16, BN folded)
//                               [128..132) w2 as 8 f16
//                               [132..148) b0 f32, [148..156) b1 f32, [156] b2 f32
#define OFF_PW   48
#define OFF_SN   208
#define OFF_Y    640                       // NDEP*HWPIX f32, layout [pix][d]
#define OFF_SRCT 615040                    // as __half*: 5 planes * HWPIX * NCH
#define OFF_DEPT (OFF_SRCT + 5 * SPLANE / 2)   // NDEP*HWPIX f32, layout [pix][d]

typedef _Float16 h2 __attribute__((ext_vector_type(2)));

__device__ __forceinline__ float fdot2_(h2 a, h2 b, float c) {
#if __has_builtin(__builtin_amdgcn_fdot2)
  return __builtin_amdgcn_fdot2(a, b, c, false);
#else
  return c + (float)a.x * (float)b.x + (float)a.y * (float)b.y;
#endif
}
__device__ __forceinline__ h2 pk_(float a, float b) {
#if __has_builtin(__builtin_amdgcn_cvt_pkrtz)
  return __builtin_bit_cast(h2, __builtin_amdgcn_cvt_pkrtz(a, b));
#else
  h2 r; r.x = (_Float16)a; r.y = (_Float16)b; return r;
#endif
}

// max over 8-lane groups (lanes l^1,l^2,l^4) — all-VALU DPP, no ds_swizzle latency
__device__ __forceinline__ float maxd8(float x) {
  int xi = __builtin_bit_cast(int, x);
  int t = __builtin_amdgcn_mov_dpp(xi, 0xB1, 0xF, 0xF, true);       // quad_perm(1,0,3,2) = xor1
  x = fmaxf(x, __builtin_bit_cast(float, t));
  xi = __builtin_bit_cast(int, x);
  t = __builtin_amdgcn_mov_dpp(xi, 0x4E, 0xF, 0xF, true);           // quad_perm(2,3,0,1) = xor2
  x = fmaxf(x, __builtin_bit_cast(float, t));
  xi = __builtin_bit_cast(int, x);
  int a = __builtin_amdgcn_update_dpp(xi, xi, 0x124, 0xF, 0x5, false); // row_ror:4, banks 0,2
  int b = __builtin_amdgcn_update_dpp(a,  xi, 0x12C, 0xF, 0xA, false); // row_ror:12, banks 1,3
  x = fmaxf(x, __builtin_bit_cast(float, b));                         // b = partner l^4
  return x;
}

// -------- packed f16 MLP 8->16->8->1 (BN pre-folded); returns last pre-activation
__device__ __forceinline__ float mlp_h(const float* __restrict__ p, const h2 x[4]) {
  const h2* w0 = (const h2*)p;          // 64 h2
  const h2* w1 = (const h2*)(p + 64);   // 64 h2
  const h2* w2 = (const h2*)(p + 128);  // 4 h2
  h2 hx[8];
#pragma unroll
  for (int o = 0; o < 8; ++o) {
    float a0 = p[132 + 2 * o], a1 = p[132 + 2 * o + 1];
#pragma unroll
    for (int i = 0; i < 4; ++i) {
      a0 = fdot2_(w0[(2 * o) * 4 + i], x[i], a0);
      a1 = fdot2_(w0[(2 * o + 1) * 4 + i], x[i], a1);
    }
    hx[o] = pk_(fmaxf(a0, 0.0f), fmaxf(a1, 0.0f));
  }
  h2 hy[4];
#pragma unroll
  for (int o = 0; o < 4; ++o) {
    float a0 = p[148 + 2 * o], a1 = p[148 + 2 * o + 1];
#pragma unroll
    for (int i = 0; i < 8; ++i) {
      a0 = fdot2_(w1[(2 * o) * 8 + i], hx[i], a0);
      a1 = fdot2_(w1[(2 * o + 1) * 8 + i], hx[i], a1);
    }
    hy[o] = pk_(fmaxf(a0, 0.0f), fmaxf(a1, 0.0f));
  }
  float acc = p[156];
#pragma unroll
  for (int i = 0; i < 4; ++i) acc = fdot2_(w2[i], hy[i], acc);
  return acc;
}

// -------- setup: proj matrices (1 lane) + f16 weight packing (lane-parallel)
__global__ void k_setup(const float* __restrict__ refP, const float* __restrict__ srcP,
                        const float* __restrict__ pw0, const float* __restrict__ pbn0,
                        const float* __restrict__ pw1, const float* __restrict__ pbn1,
                        const float* __restrict__ pw2, const float* __restrict__ pb2,
                        const float* __restrict__ sw0, const float* __restrict__ sbn0,
                        const float* __restrict__ sw1, const float* __restrict__ sbn1,
                        const float* __restrict__ sw2, const float* __restrict__ sb2,
                        float* __restrict__ ws) {
  int tid = threadIdx.x;
  if (tid == 578) {
    float a[4][8];
    for (int i = 0; i < 4; ++i)
      for (int j = 0; j < 4; ++j) { a[i][j] = refP[i * 4 + j]; a[i][4 + j] = (i == j) ? 1.0f : 0.0f; }
    for (int c = 0; c < 4; ++c) {
      int piv = c; float best = fabsf(a[c][c]);
      for (int r = c + 1; r < 4; ++r) { float t = fabsf(a[r][c]); if (t > best) { best = t; piv = r; } }
      if (piv != c) for (int j = 0; j < 8; ++j) { float t = a[c][j]; a[c][j] = a[piv][j]; a[piv][j] = t; }
      float inv = 1.0f / a[c][c];
      for (int j = 0; j < 8; ++j) a[c][j] *= inv;
      for (int r = 0; r < 4; ++r) if (r != c) {
        float f = a[r][c];
        for (int j = 0; j < 8; ++j) a[r][j] -= f * a[c][j];
      }
    }
    for (int v = 0; v < NVIEW; ++v) {
      const float* S = srcP + v * 16;
      for (int i = 0; i < 3; ++i)
        for (int j = 0; j < 4; ++j) {
          float p = S[i*4+0]*a[0][4+j] + S[i*4+1]*a[1][4+j] + S[i*4+2]*a[2][4+j] + S[i*4+3]*a[3][4+j];
          if (j < 3) ws[v * 12 + i * 3 + j] = p;
          else       ws[v * 12 + 9 + i] = p;
        }
    }
    return;
  }
  if (tid >= 578) return;
  int k = tid / 289;
  int j = tid - k * 289;
  const float* W0 = k ? sw0 : pw0;  const float* B0 = k ? sbn0 : pbn0;
  const float* W1 = k ? sw1 : pw1;  const float* B1 = k ? sbn1 : pbn1;
  const float* W2 = k ? sw2 : pw2;  const float* B2 = k ? sb2 : pb2;
  float* p = ws + (k ? OFF_SN : OFF_PW);
  __half* w0h = (__half*)p;
  __half* w1h = (__half*)(p + 64);
  __half* w2h = (__half*)(p + 128);
  if (j < 128) {
    int o = j >> 3;
    float s = B0[o] / sqrtf(B0[48 + o] + 1e-5f);
    w0h[j] = __float2half_rn(W0[j] * s * 0.25f);
  } else if (j < 256) {
    int idx = j - 128; int o = idx >> 4;
    float s = B1[o] / sqrtf(B1[24 + o] + 1e-5f);
    w1h[idx] = __float2half_rn(W1[idx] * s);
  } else if (j < 264) {
    w2h[j - 256] = __float2half_rn(W2[j - 256]);
  } else if (j < 280) {
    int o = j - 264;
    float s = B0[o] / sqrtf(B0[48 + o] + 1e-5f);
    p[132 + o] = B0[16 + o] - B0[32 + o] * s;
  } else if (j < 288) {
    int o = j - 280;
    float s = B1[o] / sqrtf(B1[24 + o] + 1e-5f);
    p[148 + o] = B1[8 + o] - B1[16 + o] * s;
  } else {
    p[156] = B2[0];
  }
}

// -------- transpose+convert (V,C,H,W) f32 -> (plane,H,W,C) f16; plane 4 = ref.
// Appended range: depth (D,H,W) -> dep_t [pix][d] f32.
__global__ __launch_bounds__(256) void k_transpose(const float* __restrict__ src,
                                                   const float* __restrict__ ref,
                                                   const float* __restrict__ depthS,
                                                   __half* __restrict__ dst,
                                                   float* __restrict__ dep_t, int total) {
  int t = blockIdx.x * 256 + threadIdx.x;
  if (t >= total) return;
  const int base = 5 * HWPIX * 4;
  if (t >= base) {                     // depth transpose
    int pix = t - base;
    float4 a, b;
    a.x = depthS[0 * HWPIX + pix]; a.y = depthS[1 * HWPIX + pix];
    a.z = depthS[2 * HWPIX + pix]; a.w = depthS[3 * HWPIX + pix];
    b.x = depthS[4 * HWPIX + pix]; b.y = depthS[5 * HWPIX + pix];
    b.z = depthS[6 * HWPIX + pix]; b.w = depthS[7 * HWPIX + pix];
    float4* o = reinterpret_cast<float4*>(dep_t + (size_t)pix * NDEP);
    o[0] = a; o[1] = b;
    return;
  }
  int c8 = t & 3;
  int vp = t >> 2;
  int v = vp / HWPIX;
  int pix = vp - v * HWPIX;
  const float* s = (v < NVIEW) ? (src + ((size_t)(v * NCH + c8 * 8)) * HWPIX + pix)
                               : (ref + ((size_t)(c8 * 8)) * HWPIX + pix);
  union { h2 h[4]; float4 f; } u;
  u.h[0] = pk_(s[0],         s[HWPIX]);
  u.h[1] = pk_(s[2 * HWPIX], s[3 * HWPIX]);
  u.h[2] = pk_(s[4 * HWPIX], s[5 * HWPIX]);
  u.h[3] = pk_(s[6 * HWPIX], s[7 * HWPIX]);
  reinterpret_cast<float4*>(dst + (size_t)vp * NCH)[c8] = u.f;
}

__device__ __forceinline__ void tap_f16(const __half* __restrict__ p, float wtf,
                                        h2 wp[16], bool first) {
  _Float16 wh = (_Float16)wtf;
  h2 wt2 = h2{wh, wh};
  const float4* q = reinterpret_cast<const float4*>(p);
#pragma unroll
  for (int i = 0; i < 4; ++i) {
    union { float4 f; h2 h[4]; } u; u.f = q[i];
#pragma unroll
    for (int c = 0; c < 4; ++c) {
      if (first) wp[4 * i + c] = u.h[c] * wt2;
      else       wp[4 * i + c] += u.h[c] * wt2;
    }
  }
}

// -------- main fused kernel. MODE 1: f16 transposed features. MODE 0: direct f32 CHW.
template <int MODE>
__global__ __launch_bounds__(256) void k_main(
    const float* __restrict__ ref, const float* __restrict__ src,
    const __half* __restrict__ srcT,
    const float* __restrict__ depthS, const float* __restrict__ dep_t,
    const float* __restrict__ wsc,
    float* __restrict__ ybuf, float* __restrict__ outVW) {
  int t = blockIdx.x * 256 + threadIdx.x;
  int d = t & 7;
  int pix = t >> 3;
  int h = pix / WW;
  int w = pix - h * WW;
  float fx = (float)w, fy = (float)h;

  h2 rc[16];
  float rcf[(MODE == 0) ? NCH : 1];
  if (MODE == 1) {
    const float4* rp = reinterpret_cast<const float4*>(srcT + (size_t)NVIEW * SPLANE + (size_t)pix * NCH);
#pragma unroll
    for (int i = 0; i < 4; ++i) {
      union { float4 f; h2 h[4]; } u; u.f = rp[i];
      rc[4*i] = u.h[0]; rc[4*i+1] = u.h[1]; rc[4*i+2] = u.h[2]; rc[4*i+3] = u.h[3];
    }
  } else {
#pragma unroll
    for (int c = 0; c < NCH; ++c) rcf[c] = ref[c * HWPIX + pix];
  }
  float dep = (MODE == 1) ? dep_t[(size_t)pix * NDEP + d] : depthS[d * HWPIX + pix];

  float ssum[NGRP];
#pragma unroll
  for (int g = 0; g < NGRP; ++g) ssum[g] = 0.0f;
  float wsum = 0.0f;

#pragma unroll 1
  for (int v = 0; v < NVIEW; ++v) {
    const float* pr = wsc + v * 12;
    float rx = fmaf(pr[0], fx, fmaf(pr[1], fy, pr[2]));
    float ry = fmaf(pr[3], fx, fmaf(pr[4], fy, pr[5]));
    float rz = fmaf(pr[6], fx, fmaf(pr[7], fy, pr[8]));
    float pz_ = fmaf(rz, dep, pr[11]);
    bool neg = (pz_ <= 0.001f);
    float px_ = neg ? (float)WW : fmaf(rx, dep, pr[9]);
    float py_ = neg ? (float)HH : fmaf(ry, dep, pr[10]);
    float rpz = neg ? 1.0f : __fdividef(1.0f, pz_);
    float ix = px_ * rpz;      // align_corners=True algebra: ix = px/pz
    float iy = py_ * rpz;
    float x0f = floorf(ix), y0f = floorf(iy);
    float wx1 = ix - x0f, wy1 = iy - y0f;
    float wx0 = 1.0f - wx1, wy0 = 1.0f - wy1;
    float x1f = x0f + 1.0f, y1f = y0f + 1.0f;
    float vx0 = (x0f >= 0.0f && x0f <= (float)(WW - 1)) ? 1.0f : 0.0f;
    float vx1 = (x1f >= 0.0f && x1f <= (float)(WW - 1)) ? 1.0f : 0.0f;
    float vy0 = (y0f >= 0.0f && y0f <= (float)(HH - 1)) ? 1.0f : 0.0f;
    float vy1 = (y1f >= 0.0f && y1f <= (float)(HH - 1)) ? 1.0f : 0.0f;
    int xa = (int)fminf(fmaxf(x0f, 0.0f), (float)(WW - 1));
    int xb = (int)fminf(fmaxf(x1f, 0.0f), (float)(WW - 1));
    int ya = (int)fminf(fmaxf(y0f, 0.0f), (float)(HH - 1));
    int yb = (int)fminf(fmaxf(y1f, 0.0f), (float)(HH - 1));
    float w00 = wx0 * wy0 * vx0 * vy0;   // zeros_pad=True
    float w01 = wx1 * wy0 * vx1 * vy0;
    float w10 = wx0 * wy1 * vx0 * vy1;
    float w11 = wx1 * wy1 * vx1 * vy1;

    float simf[NGRP];
    if (MODE == 1) {
      const __half* vbase = srcT + (size_t)v * SPLANE;
      h2 wp[16];
      tap_f16(vbase + (size_t)(ya * WW + xa) * NCH, w00, wp, true);
      tap_f16(vbase + (size_t)(ya * WW + xb) * NCH, w01, wp, false);
      tap_f16(vbase + (size_t)(yb * WW + xa) * NCH, w10, wp, false);
      tap_f16(vbase + (size_t)(yb * WW + xb) * NCH, w11, wp, false);
#pragma unroll
      for (int g = 0; g < NGRP; ++g)
        simf[g] = fdot2_(wp[2*g+1], rc[2*g+1], fdot2_(wp[2*g], rc[2*g], 0.0f));
    } else {
      const float* base = src + (size_t)v * NCH * HWPIX;
      const float* p00 = base + ya * WW + xa;
      const float* p01 = base + ya * WW + xb;
      const float* p10 = base + yb * WW + xa;
      const float* p11 = base + yb * WW + xb;
#pragma unroll
      for (int g = 0; g < NGRP; ++g) {
        float acc = 0.0f;
#pragma unroll
        for (int cc = 0; cc < 4; ++cc) {
          size_t o = (size_t)(g * 4 + cc) * HWPIX;
          float wv = w00 * p00[o] + w01 * p01[o] + w10 * p10[o] + w11 * p11[o];
          acc = fmaf(wv, rcf[g * 4 + cc], acc);
        }
        simf[g] = acc;
      }
    }

    h2 x[4];
#pragma unroll
    for (int i = 0; i < 4; ++i) x[i] = pk_(simf[2*i], simf[2*i+1]);
    float sc = mlp_h(wsc + OFF_PW, x);
    sc = maxd8(sc);                          // max over d via DPP (sigmoid monotonic)
    float vw = __fdividef(1.0f, 1.0f + __expf(-sc));
#pragma unroll
    for (int g = 0; g < NGRP; ++g) ssum[g] = fmaf(simf[g], vw, ssum[g]);
    wsum += vw;
    if (d == 0) outVW[v * HWPIX + pix] = vw;
  }

  float rw = __fdividef(1.0f, wsum);
  h2 xg[4];
#pragma unroll
  for (int i = 0; i < 4; ++i) xg[i] = pk_(ssum[2*i] * rw, ssum[2*i+1] * rw);
  float yv = mlp_h(wsc + OFF_SN, xg);
  ybuf[pix * NDEP + d] = yv;               // [pix][d] coalesced
}

// -------- score: thread-per-pixel. 9-neighbor bilinear on ybuf[pix][d] + weight dot
//          + in-register softmax over d + depth regression. Zero cross-lane ops.
__global__ __launch_bounds__(256) void k_score(
    const float* __restrict__ grid, const float* __restrict__ weight,
    const float* __restrict__ depthS, const float* __restrict__ dep_t,
    const float* __restrict__ ybuf, float* __restrict__ out, int useDT) {
  int pix = blockIdx.x * 256 + threadIdx.x;
  int h = pix / WW;
  int w = pix - h * WW;
  float sv[NDEP];
#pragma unroll
  for (int d = 0; d < NDEP; ++d) sv[d] = 0.0f;

#pragma unroll 1
  for (int n = 0; n < NNEI; ++n) {
    int gi = ((n * HH + h) * WW + w) * 2;
    float gx = grid[gi], gy = grid[gi + 1];
    float ix = ((gx + 1.0f) * (float)WW - 1.0f) * 0.5f;  // align_corners=False
    float iy = ((gy + 1.0f) * (float)HH - 1.0f) * 0.5f;
    float x0f = floorf(ix), y0f = floorf(iy);
    float wx1 = ix - x0f, wy1 = iy - y0f;
    float wx0 = 1.0f - wx1, wy0 = 1.0f - wy1;
    int xa = (int)fminf(fmaxf(x0f, 0.0f), (float)(WW - 1));
    int xb = (int)fminf(fmaxf(x0f + 1.0f, 0.0f), (float)(WW - 1));
    int ya = (int)fminf(fmaxf(y0f, 0.0f), (float)(HH - 1));
    int yb2 = (int)fminf(fmaxf(y0f + 1.0f, 0.0f), (float)(HH - 1));
    const float4* p00 = reinterpret_cast<const float4*>(ybuf + (size_t)(ya * WW + xa) * NDEP);
    const float4* p01 = reinterpret_cast<const float4*>(ybuf + (size_t)(ya * WW + xb) * NDEP);
    const float4* p10 = reinterpret_cast<const float4*>(ybuf + (size_t)(yb2 * WW + xa) * NDEP);
    const float4* p11 = reinterpret_cast<const float4*>(ybuf + (size_t)(yb2 * WW + xb) * NDEP);
    float4 a00 = p00[0], b00 = p00[1];
    float4 a01 = p01[0], b01 = p01[1];
    float4 a10 = p10[0], b10 = p10[1];
    float4 a11 = p11[0], b11 = p11[1];
    const float* v00 = (const float*)&a00;  // [0..3], b for [4..7]
    const float* v01 = (const float*)&a01;
    const float* v10 = (const float*)&a10;
    const float* v11 = (const float*)&a11;
    const float* u00 = (const float*)&b00;
    const float* u01 = (const float*)&b01;
    const float* u10 = (const float*)&b10;
    const float* u11 = (const float*)&b11;
#pragma unroll
    for (int d = 0; d < NDEP; ++d) {
      float c00 = (d < 4) ? v00[d] : u00[d - 4];
      float c01 = (d < 4) ? v01[d] : u01[d - 4];
      float c10 = (d < 4) ? v10[d] : u10[d - 4];
      float c11 = (d < 4) ? v11[d] : u11[d - 4];
      float s = wy0 * fmaf(wx0, c00, wx1 * c01) + wy1 * fmaf(wx0, c10, wx1 * c11);
      float wn = weight[((size_t)(d * NNEI + n) * HH + h) * WW + w];
      sv[d] = fmaf(s, wn, sv[d]);
    }
  }
  // in-register softmax over d + depth regression
  float m = sv[0];
#pragma unroll
  for (int d = 1; d < NDEP; ++d) m = fmaxf(m, sv[d]);
  float e[NDEP], s8 = 0.0f;
#pragma unroll
  for (int d = 0; d < NDEP; ++d) { e[d] = __expf(sv[d] - m); s8 += e[d]; }
  float r = __fdividef(1.0f, s8);
  float dpv[NDEP];
  if (useDT) {
    const float4* dp4 = reinterpret_cast<const float4*>(dep_t + (size_t)pix * NDEP);
    float4 da = dp4[0], db = dp4[1];
    dpv[0]=da.x; dpv[1]=da.y; dpv[2]=da.z; dpv[3]=da.w;
    dpv[4]=db.x; dpv[5]=db.y; dpv[6]=db.z; dpv[7]=db.w;
  } else {
#pragma unroll
    for (int d = 0; d < NDEP; ++d) dpv[d] = depthS[d * HWPIX + pix];
  }
  float dp = 0.0f;
#pragma unroll
  for (int d = 0; d < NDEP; ++d) {
    float sc = e[d] * r;
    out[HWPIX + d * HWPIX + pix] = sc;     // score
    dp = fmaf(dpv[d], sc, dp);
  }
  out[pix] = dp;                           // depth
}

extern "C" void kernel_launch(void* const* d_in, const int* in_sizes, int n_in,
                              void* d_out, int out_size, void* d_ws, size_t ws_size,
                              hipStream_t stream) {
  const float* ref    = (const float*)d_in[0];
  const float* src    = (const float*)d_in[1];
  const float* refP   = (const float*)d_in[2];
  const float* srcP   = (const float*)d_in[3];
  const float* depthS = (const float*)d_in[4];
  const float* grid   = (const float*)d_in[5];
  const float* weight = (const float*)d_in[6];
  float* out = (float*)d_out;
  float* ws  = (float*)d_ws;
  __half* srcT = (__half*)(ws + OFF_SRCT);
  float* dep_t = ws + OFF_DEPT;

  size_t need = ((size_t)OFF_DEPT + (size_t)NDEP * HWPIX) * 4;
  int mode = (ws_size >= need) ? 1 : 0;

  k_setup<<<1, 640, 0, stream>>>(refP, srcP,
                                 (const float*)d_in[7], (const float*)d_in[8],
                                 (const float*)d_in[9], (const float*)d_in[10],
                                 (const float*)d_in[11], (const float*)d_in[12],
                                 (const float*)d_in[13], (const float*)d_in[14],
                                 (const float*)d_in[15], (const float*)d_in[16],
                                 (const float*)d_in[17], (const float*)d_in[18], ws);
  if (mode == 1) {
    int total = 5 * HWPIX * 4 + HWPIX;
    k_transpose<<<(total + 255) / 256, 256, 0, stream>>>(src, ref, depthS, srcT, dep_t, total);
    k_main<1><<<(HWPIX * 8) / 256, 256, 0, stream>>>(ref, src, srcT, depthS, dep_t, ws,
                                                     ws + OFF_Y, out + 9 * HWPIX);
  } else {
    k_main<0><<<(HWPIX * 8) / 256, 256, 0, stream>>>(ref, src, srcT, depthS, dep_t, ws,
                                                     ws + OFF_Y, out + 9 * HWPIX);
  }
  k_score<<<HWPIX / 256, 256, 0, stream>>>(grid, weight, depthS, dep_t, ws + OFF_Y, out, mode);
}

// Round 6
// 89.823 us; speedup vs baseline: 1.0388x; 1.0388x over previous
//
#include <hip/hip_runtime.h>
#include <hip/hip_fp16.h>
#include <cstdint>
#include <cstddef>

#define HH 240
#define WW 320
#define HWPIX 76800
#define NVIEW 4
#define NCH 32
#define NGRP 8
#define NDEP 8
#define NNEI 9
#define SPLANE (HWPIX * NCH)   // halfs per feature plane

// ws layout (floats):
// [0..48)   proj: 4 views * 12 (rot 9 row-major, trans 3)
// [62],[63] b2 for pw / sn
// [64..)    per-lane MFMA fragment tables, per net (stride 1024 floats):
//           +0   T_w0 [64][4]  (A-frag layer0: W0' f16 / bias K-slot)
//           +256 T_w1 [64][4]  (A-frag layer1: W1' f16)
//           +512 T_b1 [64][4]  (f32 bias select per lane-half)
//           +768 T_w2 [64][4]  (f32 w2 select per lane-half)
#define OFF_TAB 64
#define OFF_Y    4096                     // NDEP*HWPIX f32, layout [pix][d]
#define OFF_SRCT 618496                   // as __half*: 5 planes * HWPIX * NCH
#define OFF_DEPT 6762496                  // NDEP*HWPIX f32, layout [pix][d]

typedef _Float16 h2 __attribute__((ext_vector_type(2)));
typedef __fp16  h8v __attribute__((ext_vector_type(8)));
typedef float f32x16 __attribute__((ext_vector_type(16)));

__device__ __forceinline__ float fdot2_(h2 a, h2 b, float c) {
#if __has_builtin(__builtin_amdgcn_fdot2)
  return __builtin_amdgcn_fdot2(a, b, c, false);
#else
  return c + (float)a.x * (float)b.x + (float)a.y * (float)b.y;
#endif
}
__device__ __forceinline__ h2 pk_(float a, float b) {
#if __has_builtin(__builtin_amdgcn_cvt_pkrtz)
  return __builtin_bit_cast(h2, __builtin_amdgcn_cvt_pkrtz(a, b));
#else
  h2 r; r.x = (_Float16)a; r.y = (_Float16)b; return r;
#endif
}
__device__ __forceinline__ float pkf_(float a, float b) {
  return __builtin_bit_cast(float, pk_(a, b));
}

__device__ __forceinline__ f32x16 mfma_(h8v a, h8v b, f32x16 c) {
  return __builtin_amdgcn_mfma_f32_32x32x16_f16(a, b, c, 0, 0, 0);
}

// max over 8-lane groups (lanes l^1,l^2,l^4) — all-VALU DPP
__device__ __forceinline__ float maxd8(float x) {
  int xi = __builtin_bit_cast(int, x);
  int t = __builtin_amdgcn_mov_dpp(xi, 0xB1, 0xF, 0xF, true);       // quad_perm xor1
  x = fmaxf(x, __builtin_bit_cast(float, t));
  xi = __builtin_bit_cast(int, x);
  t = __builtin_amdgcn_mov_dpp(xi, 0x4E, 0xF, 0xF, true);           // quad_perm xor2
  x = fmaxf(x, __builtin_bit_cast(float, t));
  xi = __builtin_bit_cast(int, x);
  int a = __builtin_amdgcn_update_dpp(xi, xi, 0x124, 0xF, 0x5, false); // row_ror:4
  int b = __builtin_amdgcn_update_dpp(a,  xi, 0x12C, 0xF, 0xA, false); // row_ror:12
  x = fmaxf(x, __builtin_bit_cast(float, b));
  return x;
}

// Wave-batched MLP 8->16->8->1 via 32x32x16 f16 MFMA.
// Batch = 64 lanes (each lane one sample, x4 = 8 f16 features).
// Layer0 bias via K-slot trick (A rows k=8 hold b0, B k=8 = 1.0).
__device__ __forceinline__ float mlp_mfma(float4 x4, h8v w0f, h8v w1f,
                                          float4 b1s, float4 w2s, float b2v,
                                          bool lo) {
  f32x16 Z = {};
  float4 xsw;
  xsw.x = __shfl_xor(x4.x, 32, 64);
  xsw.y = __shfl_xor(x4.y, 32, 64);
  xsw.z = __shfl_xor(x4.z, 32, 64);
  xsw.w = __shfl_xor(x4.w, 32, 64);
  float4 cst;
  cst.x = __builtin_bit_cast(float, 0x00003C00u);   // h2(1.0, 0) -> bias K-slot
  cst.y = 0.0f; cst.z = 0.0f; cst.w = 0.0f;
  float4 blo, bhi;
  blo.x = lo ? x4.x : cst.x;  blo.y = lo ? x4.y : cst.y;
  blo.z = lo ? x4.z : cst.z;  blo.w = lo ? x4.w : cst.w;
  bhi.x = lo ? xsw.x : cst.x; bhi.y = lo ? xsw.y : cst.y;
  bhi.z = lo ? xsw.z : cst.z; bhi.w = lo ? xsw.w : cst.w;

  float yv0 = 0.0f, yv1 = 0.0f;
#pragma unroll
  for (int bb = 0; bb < 2; ++bb) {
    float4 bin = bb ? bhi : blo;
    f32x16 acc = mfma_(w0f, __builtin_bit_cast(h8v, bin), Z);
    // lane holds sample col=l&31; regs0-7 = neurons {0-3,8-11}+4*(l>>5)
    float dw0 = pkf_(fmaxf(acc[0], 0.f), fmaxf(acc[1], 0.f));
    float dw1 = pkf_(fmaxf(acc[2], 0.f), fmaxf(acc[3], 0.f));
    float dw2 = pkf_(fmaxf(acc[4], 0.f), fmaxf(acc[5], 0.f));
    float dw3 = pkf_(fmaxf(acc[6], 0.f), fmaxf(acc[7], 0.f));
    float s0 = __shfl_xor(dw0, 32, 64);
    float s1 = __shfl_xor(dw1, 32, 64);
    float s2 = __shfl_xor(dw2, 32, 64);
    float s3 = __shfl_xor(dw3, 32, 64);
    float4 bf;                       // B-frag layer1: k-slice (l>>5)*8 = neurons
    bf.x = lo ? dw0 : s2;
    bf.y = lo ? dw1 : s3;
    bf.z = lo ? s0 : dw2;
    bf.w = lo ? s1 : dw3;
    f32x16 a2 = mfma_(w1f, __builtin_bit_cast(h8v, bf), Z);
    // lane: sample col=l&31, regs0-3 = neurons (0-3)+4*(l>>5)
    float p = fmaxf(a2[0] + b1s.x, 0.f) * w2s.x;
    p = fmaf(fmaxf(a2[1] + b1s.y, 0.f), w2s.y, p);
    p = fmaf(fmaxf(a2[2] + b1s.z, 0.f), w2s.z, p);
    p = fmaf(fmaxf(a2[3] + b1s.w, 0.f), w2s.w, p);
    p += __shfl_xor(p, 32, 64);      // combine lane-half partials
    if (bb) yv1 = p + b2v; else yv0 = p + b2v;
  }
  return lo ? yv0 : yv1;
}

// -------- prep: transpose+convert features & depth; last block = setup
__global__ __launch_bounds__(256) void k_prep(
    const float* __restrict__ src, const float* __restrict__ ref,
    const float* __restrict__ depthS,
    __half* __restrict__ dst, float* __restrict__ dep_t,
    const float* __restrict__ refP, const float* __restrict__ srcP,
    const float* __restrict__ pw0, const float* __restrict__ pbn0,
    const float* __restrict__ pw1, const float* __restrict__ pbn1,
    const float* __restrict__ pw2, const float* __restrict__ pb2,
    const float* __restrict__ sw0, const float* __restrict__ sbn0,
    const float* __restrict__ sw1, const float* __restrict__ sbn1,
    const float* __restrict__ sw2, const float* __restrict__ sb2,
    float* __restrict__ ws, int nTransBlocks) {
  if ((int)blockIdx.x == nTransBlocks) {
    int tid = threadIdx.x;
    if (tid < 128) {                 // fragment tables: net = tid>>6, lane = tid&63
      int net = tid >> 6;
      int l = tid & 63;
      int n = l & 31;
      int hi = l >> 5;
      const float* W0 = net ? sw0 : pw0;  const float* B0 = net ? sbn0 : pbn0;
      const float* W1 = net ? sw1 : pw1;  const float* B1 = net ? sbn1 : pbn1;
      const float* W2 = net ? sw2 : pw2;
      float* base = ws + OFF_TAB + net * 1024;
      // T_w0
      float4 r;
      if (hi == 0 && n < 16) {
        float s = B0[n] / sqrtf(B0[48 + n] + 1e-5f) * 0.25f;   // BN + group-mean fold
        r.x = pkf_(W0[n * 8 + 0] * s, W0[n * 8 + 1] * s);
        r.y = pkf_(W0[n * 8 + 2] * s, W0[n * 8 + 3] * s);
        r.z = pkf_(W0[n * 8 + 4] * s, W0[n * 8 + 5] * s);
        r.w = pkf_(W0[n * 8 + 6] * s, W0[n * 8 + 7] * s);
      } else if (hi == 1 && n < 16) {
        float s = B0[n] / sqrtf(B0[48 + n] + 1e-5f);
        float b0f = B0[16 + n] - B0[32 + n] * s;
        r.x = pkf_(b0f, 0.f); r.y = 0.f; r.z = 0.f; r.w = 0.f;
      } else { r.x = r.y = r.z = r.w = 0.f; }
      ((float4*)(base))[l] = r;
      // T_w1
      float4 q;
      if (n < 8) {
        float s = B1[n] / sqrtf(B1[24 + n] + 1e-5f);
        int o = n * 16 + 8 * hi;
        q.x = pkf_(W1[o + 0] * s, W1[o + 1] * s);
        q.y = pkf_(W1[o + 2] * s, W1[o + 3] * s);
        q.z = pkf_(W1[o + 4] * s, W1[o + 5] * s);
        q.w = pkf_(W1[o + 6] * s, W1[o + 7] * s);
      } else { q.x = q.y = q.z = q.w = 0.f; }
      ((float4*)(base + 256))[l] = q;
      // T_b1 (f32 bias per lane-half)
      float4 b;
      {
        float bb[4];
        for (int rr = 0; rr < 4; ++rr) {
          int o = rr + 4 * hi;
          float s = B1[o] / sqrtf(B1[24 + o] + 1e-5f);
          bb[rr] = B1[8 + o] - B1[16 + o] * s;
        }
        b.x = bb[0]; b.y = bb[1]; b.z = bb[2]; b.w = bb[3];
      }
      ((float4*)(base + 512))[l] = b;
      // T_w2
      float4 w2v;
      w2v.x = W2[0 + 4 * hi]; w2v.y = W2[1 + 4 * hi];
      w2v.z = W2[2 + 4 * hi]; w2v.w = W2[3 + 4 * hi];
      ((float4*)(base + 768))[l] = w2v;
    } else if (tid == 128) {
      ws[62] = pb2[0];
      ws[63] = sb2[0];
    } else if (tid == 129) {
      // 4x4 inverse of refP (Gauss-Jordan), proj = srcP * inv
      float a[4][8];
      for (int i = 0; i < 4; ++i)
        for (int j = 0; j < 4; ++j) { a[i][j] = refP[i * 4 + j]; a[i][4 + j] = (i == j) ? 1.0f : 0.0f; }
      for (int c = 0; c < 4; ++c) {
        int piv = c; float best = fabsf(a[c][c]);
        for (int r2 = c + 1; r2 < 4; ++r2) { float t = fabsf(a[r2][c]); if (t > best) { best = t; piv = r2; } }
        if (piv != c) for (int j = 0; j < 8; ++j) { float t = a[c][j]; a[c][j] = a[piv][j]; a[piv][j] = t; }
        float inv = 1.0f / a[c][c];
        for (int j = 0; j < 8; ++j) a[c][j] *= inv;
        for (int r2 = 0; r2 < 4; ++r2) if (r2 != c) {
          float f = a[r2][c];
          for (int j = 0; j < 8; ++j) a[r2][j] -= f * a[c][j];
        }
      }
      for (int v = 0; v < NVIEW; ++v) {
        const float* S = srcP + v * 16;
        for (int i = 0; i < 3; ++i)
          for (int j = 0; j < 4; ++j) {
            float p = S[i*4+0]*a[0][4+j] + S[i*4+1]*a[1][4+j] + S[i*4+2]*a[2][4+j] + S[i*4+3]*a[3][4+j];
            if (j < 3) ws[v * 12 + i * 3 + j] = p;
            else       ws[v * 12 + 9 + i] = p;
          }
      }
    }
    return;
  }
  int t = blockIdx.x * 256 + threadIdx.x;
  const int base = 5 * HWPIX * 4;
  if (t >= base) {                     // depth transpose -> [pix][d]
    int pix = t - base;
    float4 a, b;
    a.x = depthS[0 * HWPIX + pix]; a.y = depthS[1 * HWPIX + pix];
    a.z = depthS[2 * HWPIX + pix]; a.w = depthS[3 * HWPIX + pix];
    b.x = depthS[4 * HWPIX + pix]; b.y = depthS[5 * HWPIX + pix];
    b.z = depthS[6 * HWPIX + pix]; b.w = depthS[7 * HWPIX + pix];
    float4* o = reinterpret_cast<float4*>(dep_t + (size_t)pix * NDEP);
    o[0] = a; o[1] = b;
    return;
  }
  int c8 = t & 3;
  int vp = t >> 2;
  int v = vp / HWPIX;
  int pix = vp - v * HWPIX;
  const float* s = (v < NVIEW) ? (src + ((size_t)(v * NCH + c8 * 8)) * HWPIX + pix)
                               : (ref + ((size_t)(c8 * 8)) * HWPIX + pix);
  union { h2 h[4]; float4 f; } u;
  u.h[0] = pk_(s[0],         s[HWPIX]);
  u.h[1] = pk_(s[2 * HWPIX], s[3 * HWPIX]);
  u.h[2] = pk_(s[4 * HWPIX], s[5 * HWPIX]);
  u.h[3] = pk_(s[6 * HWPIX], s[7 * HWPIX]);
  reinterpret_cast<float4*>(dst + (size_t)vp * NCH)[c8] = u.f;
}

__device__ __forceinline__ void tap_f16(const __half* __restrict__ p, float wtf,
                                        h2 wp[16], bool first) {
  _Float16 wh = (_Float16)wtf;
  h2 wt2 = h2{wh, wh};
  const float4* q = reinterpret_cast<const float4*>(p);
#pragma unroll
  for (int i = 0; i < 4; ++i) {
    union { float4 f; h2 h[4]; } u; u.f = q[i];
#pragma unroll
    for (int c = 0; c < 4; ++c) {
      if (first) wp[4 * i + c] = u.h[c] * wt2;
      else       wp[4 * i + c] += u.h[c] * wt2;
    }
  }
}

// -------- main fused kernel: warp+corr+pw-net(MFMA)+aggregate+sn-net(MFMA)
__global__ __launch_bounds__(256) void k_main(
    const __half* __restrict__ srcT, const float* __restrict__ dep_t,
    const float* __restrict__ wsc,
    float* __restrict__ ybuf, float* __restrict__ outVW) {
  int t = blockIdx.x * 256 + threadIdx.x;
  int lane = threadIdx.x & 63;
  bool lo = lane < 32;
  int d = t & 7;
  int pix = t >> 3;
  int h = pix / WW;
  int w = pix - h * WW;
  float fx = (float)w, fy = (float)h;

  // pw-net fragments
  const h8v* Tw0p = (const h8v*)(wsc + OFF_TAB);
  const h8v* Tw1p = (const h8v*)(wsc + OFF_TAB + 256);
  h8v w0f_pw = Tw0p[lane];
  h8v w1f_pw = Tw1p[lane];
  float4 b1s_pw = ((const float4*)(wsc + OFF_TAB + 512))[lane];
  float4 w2s_pw = ((const float4*)(wsc + OFF_TAB + 768))[lane];
  float b2_pw = wsc[62];

  h2 rc[16];
  {
    const float4* rp = reinterpret_cast<const float4*>(srcT + (size_t)NVIEW * SPLANE + (size_t)pix * NCH);
#pragma unroll
    for (int i = 0; i < 4; ++i) {
      union { float4 f; h2 h[4]; } u; u.f = rp[i];
      rc[4*i] = u.h[0]; rc[4*i+1] = u.h[1]; rc[4*i+2] = u.h[2]; rc[4*i+3] = u.h[3];
    }
  }
  float dep = dep_t[(size_t)pix * NDEP + d];

  float ssum[NGRP];
#pragma unroll
  for (int g = 0; g < NGRP; ++g) ssum[g] = 0.0f;
  float wsum = 0.0f;

#pragma unroll 1
  for (int v = 0; v < NVIEW; ++v) {
    const float* pr = wsc + v * 12;
    float rx = fmaf(pr[0], fx, fmaf(pr[1], fy, pr[2]));
    float ry = fmaf(pr[3], fx, fmaf(pr[4], fy, pr[5]));
    float rz = fmaf(pr[6], fx, fmaf(pr[7], fy, pr[8]));
    float pz_ = fmaf(rz, dep, pr[11]);
    bool neg = (pz_ <= 0.001f);
    float px_ = neg ? (float)WW : fmaf(rx, dep, pr[9]);
    float py_ = neg ? (float)HH : fmaf(ry, dep, pr[10]);
    float rpz = neg ? 1.0f : __fdividef(1.0f, pz_);
    float ix = px_ * rpz;      // align_corners=True algebra: ix = px/pz
    float iy = py_ * rpz;
    float x0f = floorf(ix), y0f = floorf(iy);
    float wx1 = ix - x0f, wy1 = iy - y0f;
    float wx0 = 1.0f - wx1, wy0 = 1.0f - wy1;
    float x1f = x0f + 1.0f, y1f = y0f + 1.0f;
    float vx0 = (x0f >= 0.0f && x0f <= (float)(WW - 1)) ? 1.0f : 0.0f;
    float vx1 = (x1f >= 0.0f && x1f <= (float)(WW - 1)) ? 1.0f : 0.0f;
    float vy0 = (y0f >= 0.0f && y0f <= (float)(HH - 1)) ? 1.0f : 0.0f;
    float vy1 = (y1f >= 0.0f && y1f <= (float)(HH - 1)) ? 1.0f : 0.0f;
    int xa = (int)fminf(fmaxf(x0f, 0.0f), (float)(WW - 1));
    int xb = (int)fminf(fmaxf(x1f, 0.0f), (float)(WW - 1));
    int ya = (int)fminf(fmaxf(y0f, 0.0f), (float)(HH - 1));
    int yb = (int)fminf(fmaxf(y1f, 0.0f), (float)(HH - 1));
    float w00 = wx0 * wy0 * vx0 * vy0;   // zeros_pad=True
    float w01 = wx1 * wy0 * vx1 * vy0;
    float w10 = wx0 * wy1 * vx0 * vy1;
    float w11 = wx1 * wy1 * vx1 * vy1;

    float simf[NGRP];
    {
      const __half* vbase = srcT + (size_t)v * SPLANE;
      h2 wp[16];
      tap_f16(vbase + (size_t)(ya * WW + xa) * NCH, w00, wp, true);
      tap_f16(vbase + (size_t)(ya * WW + xb) * NCH, w01, wp, false);
      tap_f16(vbase + (size_t)(yb * WW + xa) * NCH, w10, wp, false);
      tap_f16(vbase + (size_t)(yb * WW + xb) * NCH, w11, wp, false);
#pragma unroll
      for (int g = 0; g < NGRP; ++g)
        simf[g] = fdot2_(wp[2*g+1], rc[2*g+1], fdot2_(wp[2*g], rc[2*g], 0.0f));
    }

    float4 xp;
    xp.x = pkf_(simf[0], simf[1]);
    xp.y = pkf_(simf[2], simf[3]);
    xp.z = pkf_(simf[4], simf[5]);
    xp.w = pkf_(simf[6], simf[7]);
    float sc = mlp_mfma(xp, w0f_pw, w1f_pw, b1s_pw, w2s_pw, b2_pw, lo);
    sc = maxd8(sc);                          // max over d (sigmoid monotonic)
    float vw = __fdividef(1.0f, 1.0f + __expf(-sc));
#pragma unroll
    for (int g = 0; g < NGRP; ++g) ssum[g] = fmaf(simf[g], vw, ssum[g]);
    wsum += vw;
    if (d == 0) outVW[v * HWPIX + pix] = vw;
  }

  float rw = __fdividef(1.0f, wsum);
  float4 xg;
  xg.x = pkf_(ssum[0] * rw, ssum[1] * rw);
  xg.y = pkf_(ssum[2] * rw, ssum[3] * rw);
  xg.z = pkf_(ssum[4] * rw, ssum[5] * rw);
  xg.w = pkf_(ssum[6] * rw, ssum[7] * rw);
  // sn-net fragments (loaded late to limit live range)
  h8v w0f_sn = ((const h8v*)(wsc + OFF_TAB + 1024))[lane];
  h8v w1f_sn = ((const h8v*)(wsc + OFF_TAB + 1024 + 256))[lane];
  float4 b1s_sn = ((const float4*)(wsc + OFF_TAB + 1024 + 512))[lane];
  float4 w2s_sn = ((const float4*)(wsc + OFF_TAB + 1024 + 768))[lane];
  float b2_sn = wsc[63];
  float yv = mlp_mfma(xg, w0f_sn, w1f_sn, b1s_sn, w2s_sn, b2_sn, lo);
  ybuf[pix * NDEP + d] = yv;               // [pix][d] coalesced
}

// -------- score: thread-per-pixel, in-register softmax over d
__global__ __launch_bounds__(256) void k_score(
    const float* __restrict__ grid, const float* __restrict__ weight,
    const float* __restrict__ dep_t, const float* __restrict__ ybuf,
    float* __restrict__ out) {
  int pix = blockIdx.x * 256 + threadIdx.x;
  int h = pix / WW;
  int w = pix - h * WW;
  float sv[NDEP];
#pragma unroll
  for (int d = 0; d < NDEP; ++d) sv[d] = 0.0f;

#pragma unroll 1
  for (int n = 0; n < NNEI; ++n) {
    int gi = ((n * HH + h) * WW + w) * 2;
    float gx = grid[gi], gy = grid[gi + 1];
    float ix = ((gx + 1.0f) * (float)WW - 1.0f) * 0.5f;  // align_corners=False
    float iy = ((gy + 1.0f) * (float)HH - 1.0f) * 0.5f;
    float x0f = floorf(ix), y0f = floorf(iy);
    float wx1 = ix - x0f, wy1 = iy - y0f;
    float wx0 = 1.0f - wx1, wy0 = 1.0f - wy1;
    int xa = (int)fminf(fmaxf(x0f, 0.0f), (float)(WW - 1));
    int xb = (int)fminf(fmaxf(x0f + 1.0f, 0.0f), (float)(WW - 1));
    int ya = (int)fminf(fmaxf(y0f, 0.0f), (float)(HH - 1));
    int yb2 = (int)fminf(fmaxf(y0f + 1.0f, 0.0f), (float)(HH - 1));
    const float4* p00 = reinterpret_cast<const float4*>(ybuf + (size_t)(ya * WW + xa) * NDEP);
    const float4* p01 = reinterpret_cast<const float4*>(ybuf + (size_t)(ya * WW + xb) * NDEP);
    const float4* p10 = reinterpret_cast<const float4*>(ybuf + (size_t)(yb2 * WW + xa) * NDEP);
    const float4* p11 = reinterpret_cast<const float4*>(ybuf + (size_t)(yb2 * WW + xb) * NDEP);
    float4 a00 = p00[0], b00 = p00[1];
    float4 a01 = p01[0], b01 = p01[1];
    float4 a10 = p10[0], b10 = p10[1];
    float4 a11 = p11[0], b11 = p11[1];
    const float* v00 = (const float*)&a00;
    const float* v01 = (const float*)&a01;
    const float* v10 = (const float*)&a10;
    const float* v11 = (const float*)&a11;
    const float* u00 = (const float*)&b00;
    const float* u01 = (const float*)&b01;
    const float* u10 = (const float*)&b10;
    const float* u11 = (const float*)&b11;
#pragma unroll
    for (int d = 0; d < NDEP; ++d) {
      float c00 = (d < 4) ? v00[d] : u00[d - 4];
      float c01 = (d < 4) ? v01[d] : u01[d - 4];
      float c10 = (d < 4) ? v10[d] : u10[d - 4];
      float c11 = (d < 4) ? v11[d] : u11[d - 4];
      float s = wy0 * fmaf(wx0, c00, wx1 * c01) + wy1 * fmaf(wx0, c10, wx1 * c11);
      float wn = weight[((size_t)(d * NNEI + n) * HH + h) * WW + w];
      sv[d] = fmaf(s, wn, sv[d]);
    }
  }
  float m = sv[0];
#pragma unroll
  for (int d = 1; d < NDEP; ++d) m = fmaxf(m, sv[d]);
  float e[NDEP], s8 = 0.0f;
#pragma unroll
  for (int d = 0; d < NDEP; ++d) { e[d] = __expf(sv[d] - m); s8 += e[d]; }
  float r = __fdividef(1.0f, s8);
  const float4* dp4 = reinterpret_cast<const float4*>(dep_t + (size_t)pix * NDEP);
  float4 da = dp4[0], db = dp4[1];
  float dpv[NDEP] = {da.x, da.y, da.z, da.w, db.x, db.y, db.z, db.w};
  float dp = 0.0f;
#pragma unroll
  for (int d = 0; d < NDEP; ++d) {
    float sc = e[d] * r;
    out[HWPIX + d * HWPIX + pix] = sc;     // score
    dp = fmaf(dpv[d], sc, dp);
  }
  out[pix] = dp;                           // depth
}

extern "C" void kernel_launch(void* const* d_in, const int* in_sizes, int n_in,
                              void* d_out, int out_size, void* d_ws, size_t ws_size,
                              hipStream_t stream) {
  const float* ref    = (const float*)d_in[0];
  const float* src    = (const float*)d_in[1];
  const float* refP   = (const float*)d_in[2];
  const float* srcP   = (const float*)d_in[3];
  const float* depthS = (const float*)d_in[4];
  const float* grid   = (const float*)d_in[5];
  const float* weight = (const float*)d_in[6];
  float* out = (float*)d_out;
  float* ws  = (float*)d_ws;
  __half* srcT = (__half*)(ws + OFF_SRCT);
  float* dep_t = ws + OFF_DEPT;

  int transThreads = 5 * HWPIX * 4 + HWPIX;
  int nTransBlocks = transThreads / 256;            // exact: 1612800/256 = 6300

  k_prep<<<nTransBlocks + 1, 256, 0, stream>>>(
      src, ref, depthS, srcT, dep_t, refP, srcP,
      (const float*)d_in[7],  (const float*)d_in[8],
      (const float*)d_in[9],  (const float*)d_in[10],
      (const float*)d_in[11], (const float*)d_in[12],
      (const float*)d_in[13], (const float*)d_in[14],
      (const float*)d_in[15], (const float*)d_in[16],
      (const float*)d_in[17], (const float*)d_in[18],
      ws, nTransBlocks);
  k_main<<<(HWPIX * 8) / 256, 256, 0, stream>>>(srcT, dep_t, ws, ws + OFF_Y, out + 9 * HWPIX);
  k_score<<<HWPIX / 256, 256, 0, stream>>>(grid, weight, dep_t, ws + OFF_Y, out);
}